// Round 6
// baseline (8758.685 us; speedup 1.0000x reference)
//
#include <hip/hip_runtime.h>
#include <stdint.h>
#include <stddef.h>

// Problem dims
#define B_ 1024
#define S_ 128
#define D_ 256
#define H_ 2048
#define O_ 10
#define V_ 10

// Round-9: persistent kernel + W RESIDENT IN LDS + barrier-free K-loop.
// Evidence chain: r0/r1/r3 (three schedules) all 17.2-18.2 us/step; r8
// persistent+flush = 30 us/step with MfmaUtil 12% -> matrix pipes idle 88%,
// W re-streamed every step (FETCH 21 MB/step). Shared structural costs:
// W restaged through L2+LDS every step, and 2-barriers-per-K-iter lockstep.
// Fix: BN=32 per WG -> W-slice = 32x2048x2B = 128 KB: fits LDS, staged ONCE,
// reused all 127 steps (LDS survives the per-step L2 invalidate). K-loop has
// NO DMA, NO LDS writes, NO barriers: A-frags direct from global (16 rows x
// 64B contiguous per v8s load), B-frags ds_read_b128 from resident LDS,
// software-pipelined 8 chunks deep. 4 waves (1/SIMD), wave tile 64x32.
// Step sync: r5-proven AGENT-scope release/spin/acquire over 64 WGs/group.
#define BMW 256                       // rows per WG (4 waves x 64)
#define BNW 32                        // cols per WG = resident W slice
#define KCH 64                        // K-chunks of 32 (K = 2048)
#define PA 8                          // A-pipeline depth (chunks)
#define PB 4                          // B-pipeline depth (chunks)
#define SMEM2_BYTES (BNW * H_ * 2)    // 131072 B = 128 KB resident W
#define NGRP2 4                       // 4 row-groups of 256 rows
#define GRP_WGS 64                    // 64 col-WGs per group

// fallback (round-3 kernel) config
#define BM 128
#define BN 64
#define BK 128
#define NKT (H_ / BK)
#define NSTG 3
#define STG_ELEMS ((BM + BN) * BK)
#define SMEM_BYTES (NSTG * STG_ELEMS * 2)   // 144 KB

typedef unsigned short u16;
typedef short v8s __attribute__((ext_vector_type(8)));    // 8 x bf16 (4 VGPRs)
typedef float v4f __attribute__((ext_vector_type(4)));    // 4 x f32 MFMA C/D
typedef u16 u16x4 __attribute__((ext_vector_type(4)));

__device__ __forceinline__ u16 f2bf(float f) {
  unsigned int u = __float_as_uint(f);
  u += 0x7FFFu + ((u >> 16) & 1u);   // RNE
  return (u16)(u >> 16);
}
__device__ __forceinline__ float bf2f(u16 h) {
  return __uint_as_float(((unsigned int)h) << 16);
}
__device__ __forceinline__ float fast_tanh(float x) {
  float e = __expf(2.0f * x);
  return 1.0f - 2.0f / (e + 1.0f);
}
__device__ __forceinline__ void gl2lds16(const void* g, void* l) {
  __builtin_amdgcn_global_load_lds(
      (const __attribute__((address_space(1))) uint32_t*)g,
      (__attribute__((address_space(3))) uint32_t*)l, 16, 0, 0);
}

// ---------------- Txh[v][h] = b_hx[h] + sum_d embed[v][d]*W_hx[h][d] ----------------
__global__ __launch_bounds__(256) void make_table(const float* __restrict__ embed,
                                                  const float* __restrict__ W_hx,
                                                  const float* __restrict__ b_hx,
                                                  float* __restrict__ Txh) {
  int idx = blockIdx.x * 256 + threadIdx.x;   // 10*2048 = 20480
  int v = idx >> 11, h = idx & 2047;
  const float4* e4 = (const float4*)(embed + v * D_);
  const float4* w4 = (const float4*)(W_hx + (size_t)h * D_);
  float s = b_hx[h];
#pragma unroll 4
  for (int d = 0; d < D_ / 4; ++d) {
    float4 a = e4[d], b = w4[d];
    s = fmaf(a.x, b.x, s); s = fmaf(a.y, b.y, s);
    s = fmaf(a.z, b.z, s); s = fmaf(a.w, b.w, s);
  }
  Txh[idx] = s;
}

// ---------------- W_hh (f32) -> bf16, same [N][K] layout ----------------
__global__ __launch_bounds__(256) void conv_w(const float* __restrict__ W,
                                              u16* __restrict__ Wb) {
  int i = blockIdx.x * 256 + threadIdx.x;
  float4 w = ((const float4*)W)[i];
  u16x4 o = { f2bf(w.x), f2bf(w.y), f2bf(w.z), f2bf(w.w) };
  ((u16x4*)Wb)[i] = o;
}

// ---------------- h0[b][j] = tanh(Txh[x[b,0]][j]) ----------------
__global__ __launch_bounds__(256) void init_h0(const float* __restrict__ Txh,
                                               const int* __restrict__ x,
                                               u16* __restrict__ H0) {
  int idx = blockIdx.x * 256 + threadIdx.x;   // 2M
  int b = idx >> 11, j = idx & 2047;
  int xv = x[b * S_];
  H0[idx] = f2bf(fast_tanh(Txh[xv * H_ + j]));
}

// ---------------- persistent RNN: all 127 steps, W resident in LDS ----------------
// WG bid: group g = bid>>6 -> rows [g*256, g*256+256); bn = (bid&63)*32.
// W-slice [32 x 2048] staged once, XOR-swizzled chunks: LDS slot (n, c)
// holds global chunk c ^ (n&15) -> read of chunk cg at slot cg ^ lane16
// with n&15 == lane16 is conflict-free (2-way on b128 = free, m136).
// K-loop: per chunk kc (K=32): 4 A-frag global v8s loads (16 rows x 64B,
// coalesced) + 2 B ds_read_b128 + 8 MFMA. Pipelined PA=8 / PB=4 deep via
// statically-indexed register arrays (full unroll -> rule-20 safe).
// Compiler emits exact counted vmcnt/lgkm waits (no barriers to force drains).

__global__ __launch_bounds__(256, 1) void rnn_persist(const u16* __restrict__ Wb,
                                                      const float* __restrict__ Txh,
                                                      const int* __restrict__ x,
                                                      const float* __restrict__ b_hh,
                                                      u16* __restrict__ Ha,
                                                      u16* __restrict__ Hb,
                                                      unsigned int* __restrict__ cnt) {
  extern __shared__ __align__(16) u16 Wres[];   // [32][2048] bf16, swizzled

  const int tid = threadIdx.x;                 // 0..255 (4 waves, 1 per SIMD)
  const int bid = blockIdx.x;
  const int g = bid >> 6;                      // row-group 0..3
  const int bm = g * BMW;
  const int bn = (bid & 63) * BNW;

  const int w = tid >> 6, l = tid & 63;
  const int lane16 = l & 15, quad = l >> 4;
  const int rbase = bm + w * 64;               // wave rows [rbase, rbase+64)

  // ---- one-time: stage W slice into LDS (once for all 127 steps) ----
#pragma unroll
  for (int i2 = 0; i2 < 32; ++i2) {
    // dest slot s = i2*256 + tid  (n = i2, c = tid); holds global chunk c^(n&15)
    const u16* src = Wb + (size_t)(bn + i2) * H_ + (size_t)(tid ^ (i2 & 15)) * 8;
    u16* dst = Wres + (size_t)(i2 * 256 + (w << 6)) * 8;   // wave-uniform base
    gl2lds16(src, dst);
  }
  __syncthreads();   // drains vmcnt -> W resident and visible

  // step-invariant epilogue constants
  float bh[2];
#pragma unroll
  for (int j = 0; j < 2; ++j) bh[j] = b_hh[bn + j * 16 + lane16];

  for (int t = 1; t < S_; ++t) {
    const u16* Hin = (t & 1) ? Ha : Hb;
    u16* Hout = (t & 1) ? Hb : Ha;

    // per-step A addressing (element offsets into Hin)
    size_t aoff[4];
#pragma unroll
    for (int i = 0; i < 4; ++i)
      aoff[i] = (size_t)(rbase + i * 16 + lane16) * H_ + quad * 8;

    v4f acc[4][2];
#pragma unroll
    for (int i = 0; i < 4; ++i)
#pragma unroll
      for (int j = 0; j < 2; ++j) acc[i][j] = (v4f){0.f, 0.f, 0.f, 0.f};

    v8s ar[PA][4];   // A pipeline: 8 chunks x 4 m-subtiles (128 VGPR)
    v8s br[PB][2];   // B pipeline: 4 chunks x 2 n-subtiles (32 VGPR)

#define ARISS(kc) do {                                                      \
    _Pragma("unroll")                                                       \
    for (int i_ = 0; i_ < 4; ++i_)                                          \
      ar[(kc) & (PA - 1)][i_] = *(const v8s*)(Hin + aoff[i_] + (kc) * 32);  \
  } while (0)
#define BRISS(kc) do {                                                      \
    const int slot_ = (((kc) >> 2) << 4) |                                  \
                      ((((((kc) & 3) << 2) | quad)) ^ lane16);              \
    _Pragma("unroll")                                                       \
    for (int j_ = 0; j_ < 2; ++j_)                                          \
      br[(kc) & (PB - 1)][j_] =                                             \
          *(const v8s*)&Wres[(size_t)(((j_ * 16 + lane16) << 11) |          \
                                      (slot_ << 3))];                       \
  } while (0)
#define MMCH(kc) do {                                                       \
    _Pragma("unroll")                                                       \
    for (int i_ = 0; i_ < 4; ++i_)                                          \
      _Pragma("unroll")                                                     \
      for (int j_ = 0; j_ < 2; ++j_)                                        \
        acc[i_][j_] = __builtin_amdgcn_mfma_f32_16x16x32_bf16(              \
            ar[(kc) & (PA - 1)][i_], br[(kc) & (PB - 1)][j_],               \
            acc[i_][j_], 0, 0, 0);                                          \
  } while (0)

    // pipeline prologue
#pragma unroll
    for (int p = 0; p < PA; ++p) ARISS(p);
#pragma unroll
    for (int p = 0; p < PB; ++p) BRISS(p);

    // barrier-free K-loop (64 chunks, fully unrolled; static slot indices)
#pragma unroll
    for (int kc = 0; kc < KCH; ++kc) {
      MMCH(kc);
      if (kc + PA < KCH) ARISS(kc + PA);
      if (kc + PB < KCH) BRISS(kc + PB);
    }
#undef ARISS
#undef BRISS
#undef MMCH

    // epilogue: C/D layout col=lane&15, row=quad*4+reg  [m89-verified]
#pragma unroll
    for (int i = 0; i < 4; ++i) {
#pragma unroll
      for (int r = 0; r < 4; ++r) {
        int row = rbase + i * 16 + quad * 4 + r;
        const float* trow = Txh + x[row * S_ + t] * H_;
        u16* orow = Hout + (size_t)row * H_;
#pragma unroll
        for (int j = 0; j < 2; ++j) {
          int col = bn + j * 16 + lane16;
          float v = acc[i][j][r] + trow[col] + bh[j];
          orow[col] = f2bf(fast_tanh(v));
        }
      }
    }

    if (t + 1 < S_) {
      // group barrier (64 WGs): __syncthreads drains stores to L2; tid0
      // release-add (wbl2) -> relaxed spin -> acq_rel add (inv). W is in
      // LDS, untouched by the invalidate. Proven recipe (r5, passed).
      __syncthreads();
      if (tid == 0) {
        unsigned int* c = cnt + g * S_ + t;
        __hip_atomic_fetch_add(c, 1u, __ATOMIC_RELEASE, __HIP_MEMORY_SCOPE_AGENT);
        while (__hip_atomic_load(c, __ATOMIC_RELAXED, __HIP_MEMORY_SCOPE_AGENT) < GRP_WGS)
          __builtin_amdgcn_s_sleep(2);
        (void)__hip_atomic_fetch_add(c, 0u, __ATOMIC_ACQ_REL, __HIP_MEMORY_SCOPE_AGENT);
      }
      __syncthreads();
    }
  }
}

// ---------------- fallback: one recurrence step (round-3 verified kernel) ----------------
__global__ __launch_bounds__(256, 1) void rnn_step(const u16* __restrict__ Hin,
                                                   const u16* __restrict__ Wb,
                                                   const float* __restrict__ Txh,
                                                   const int* __restrict__ x,
                                                   const float* __restrict__ b_hh,
                                                   u16* __restrict__ Hout,
                                                   int t) {
  extern __shared__ __align__(16) u16 smem[];

  const int tid = threadIdx.x;
  const int bid = blockIdx.x;
  const int xcd = bid & 7;
  const int sl  = bid >> 3;
  const int xr = xcd >> 2, xc = xcd & 3;
  const int bm = (xr * 4 + (sl >> 3)) * BM;
  const int bn = (xc * 8 + (sl & 7)) * BN;

  const int w = tid >> 6, l = tid & 63;
  const int wr = w >> 1, wc = w & 1;
  const int lane16 = l & 15, quad = l >> 4;
  const int wbase = w << 6;

  unsigned offA[8], offB[4];
#pragma unroll
  for (int i = 0; i < 8; ++i) {
    int s = i * 256 + tid;
    int m = s >> 4;
    int cg = (s & 15) ^ (m & 15);
    offA[i] = (unsigned)((bm + m) * H_ + cg * 8);
  }
#pragma unroll
  for (int i = 0; i < 4; ++i) {
    int s = i * 256 + tid;
    int n = s >> 4;
    int cg = (s & 15) ^ (n & 15);
    offB[i] = (unsigned)((bn + n) * H_ + cg * 8);
  }

#define STAGE1(stg, kbase) do {                                             \
    u16* As_ = smem + (stg) * STG_ELEMS;                                    \
    u16* Bs_ = As_ + BM * BK;                                               \
    _Pragma("unroll")                                                       \
    for (int i_ = 0; i_ < 8; ++i_)                                          \
      gl2lds16(Hin + offA[i_] + (kbase), As_ + (size_t)(i_ * 256 + wbase) * 8); \
    _Pragma("unroll")                                                       \
    for (int i_ = 0; i_ < 4; ++i_)                                          \
      gl2lds16(Wb + offB[i_] + (kbase), Bs_ + (size_t)(i_ * 256 + wbase) * 8);  \
  } while (0)

  v4f acc[4][2];
#pragma unroll
  for (int i = 0; i < 4; ++i)
#pragma unroll
    for (int j = 0; j < 2; ++j) acc[i][j] = (v4f){0.f, 0.f, 0.f, 0.f};

  STAGE1(0, 0);
  STAGE1(1, BK);

  for (int kt = 0; kt < NKT; ++kt) {
    asm volatile("s_waitcnt lgkmcnt(0)" ::: "memory");
    __builtin_amdgcn_s_barrier();
    asm volatile("" ::: "memory");

    if (kt + 2 < NKT) STAGE1((kt + 2) % 3, (kt + 2) * BK);

    if (kt < NKT - 2)       asm volatile("s_waitcnt vmcnt(24)" ::: "memory");
    else if (kt == NKT - 2) asm volatile("s_waitcnt vmcnt(12)" ::: "memory");
    else                    asm volatile("s_waitcnt vmcnt(0)"  ::: "memory");

    __builtin_amdgcn_s_barrier();
    asm volatile("" ::: "memory");

    const u16* Asb = smem + (kt % 3) * STG_ELEMS;
    const u16* Bsb = Asb + BM * BK;

    v8s aX[4], bX[2], aY[4], bY[2];
#define LDSET(AV, BV, kc) do {                                              \
    const int cc_ = (kc) * 4 + quad;                                        \
    _Pragma("unroll")                                                       \
    for (int i_ = 0; i_ < 4; ++i_) {                                        \
      int m_ = wr * 64 + i_ * 16 + lane16;                                  \
      AV[i_] = *(const v8s*)&Asb[(size_t)(m_ * 16 + (cc_ ^ lane16)) * 8];   \
    }                                                                       \
    _Pragma("unroll")                                                       \
    for (int j_ = 0; j_ < 2; ++j_) {                                        \
      int n_ = wc * 32 + j_ * 16 + lane16;                                  \
      BV[j_] = *(const v8s*)&Bsb[(size_t)(n_ * 16 + (cc_ ^ lane16)) * 8];   \
    }                                                                       \
  } while (0)
#define MM(AV, BV) do {                                                     \
    _Pragma("unroll")                                                       \
    for (int i_ = 0; i_ < 4; ++i_)                                          \
      _Pragma("unroll")                                                     \
      for (int j_ = 0; j_ < 2; ++j_)                                        \
        acc[i_][j_] = __builtin_amdgcn_mfma_f32_16x16x32_bf16(              \
            AV[i_], BV[j_], acc[i_][j_], 0, 0, 0);                          \
  } while (0)

    LDSET(aX, bX, 0);
    LDSET(aY, bY, 1);
    __builtin_amdgcn_s_setprio(1);
    MM(aX, bX);
    LDSET(aX, bX, 2);
    MM(aY, bY);
    LDSET(aY, bY, 3);
    MM(aX, bX);
    MM(aY, bY);
    __builtin_amdgcn_s_setprio(0);
#undef LDSET
#undef MM
  }
#undef STAGE1

  float bh[2];
#pragma unroll
  for (int j = 0; j < 2; ++j) bh[j] = b_hh[bn + wc * 32 + j * 16 + lane16];
#pragma unroll
  for (int i = 0; i < 4; ++i) {
#pragma unroll
    for (int r = 0; r < 4; ++r) {
      int row = bm + wr * 64 + i * 16 + quad * 4 + r;
      const float* trow = Txh + x[row * S_ + t] * H_;
      u16* orow = Hout + (size_t)row * H_;
#pragma unroll
      for (int j = 0; j < 2; ++j) {
        int col = bn + wc * 32 + j * 16 + lane16;
        float v = acc[i][j][r] + trow[col] + bh[j];
        orow[col] = f2bf(fast_tanh(v));
      }
    }
  }
}

// ---------------- o = hT @ W_oh^T + b_oh ; softmax over 10 ----------------
__global__ __launch_bounds__(256) void out_softmax(const u16* __restrict__ Hf,
                                                   const float* __restrict__ W_oh,
                                                   const float* __restrict__ b_oh,
                                                   float* __restrict__ out) {
  int b = blockIdx.x, tid = threadIdx.x;
  float hv[8];
  const u16* hr = Hf + (size_t)b * H_ + tid * 8;
#pragma unroll
  for (int u = 0; u < 8; ++u) hv[u] = bf2f(hr[u]);
  float acc[O_];
#pragma unroll
  for (int i = 0; i < O_; ++i) {
    const float* wr = W_oh + (size_t)i * H_ + tid * 8;
    float s = 0.f;
#pragma unroll
    for (int u = 0; u < 8; ++u) s = fmaf(hv[u], wr[u], s);
    acc[i] = s;
  }
#pragma unroll
  for (int off = 32; off > 0; off >>= 1)
#pragma unroll
    for (int i = 0; i < O_; ++i) acc[i] += __shfl_down(acc[i], off);
  __shared__ float red[4][O_];
  if ((tid & 63) == 0)
#pragma unroll
    for (int i = 0; i < O_; ++i) red[tid >> 6][i] = acc[i];
  __syncthreads();
  if (tid == 0) {
    float o[O_], mx = -1e30f;
#pragma unroll
    for (int i = 0; i < O_; ++i) {
      o[i] = red[0][i] + red[1][i] + red[2][i] + red[3][i] + b_oh[i];
      mx = fmaxf(mx, o[i]);
    }
    float se = 0.f;
#pragma unroll
    for (int i = 0; i < O_; ++i) { o[i] = __expf(o[i] - mx); se += o[i]; }
    float inv = 1.f / se;
#pragma unroll
    for (int i = 0; i < O_; ++i) out[b * O_ + i] = o[i] * inv;
  }
}

extern "C" void kernel_launch(void* const* d_in, const int* in_sizes, int n_in,
                              void* d_out, int out_size, void* d_ws, size_t ws_size,
                              hipStream_t stream) {
  const int*   x     = (const int*)  d_in[0];
  const float* embed = (const float*)d_in[1];
  const float* W_hx  = (const float*)d_in[2];
  const float* b_hx  = (const float*)d_in[3];
  const float* W_hh  = (const float*)d_in[4];
  const float* b_hh  = (const float*)d_in[5];
  const float* W_oh  = (const float*)d_in[6];
  const float* b_oh  = (const float*)d_in[7];
  float* out = (float*)d_out;

  static bool attr_set = false;
  if (!attr_set) {
    (void)hipFuncSetAttribute(reinterpret_cast<const void*>(rnn_persist),
                              hipFuncAttributeMaxDynamicSharedMemorySize, SMEM2_BYTES);
    (void)hipFuncSetAttribute(reinterpret_cast<const void*>(rnn_step),
                              hipFuncAttributeMaxDynamicSharedMemorySize, SMEM_BYTES);
    attr_set = true;
  }

  // workspace: Txh 80KB | Wb 8MB | Ha 4MB | Hb 4MB | cnt 4KB  (~16.1 MB)
  char* ws = (char*)d_ws;
  float* Txh = (float*)ws;
  u16* Wb = (u16*)(ws + (80 << 10));
  u16* Ha = (u16*)(ws + (80 << 10) + (8 << 20));
  u16* Hb = (u16*)(ws + (80 << 10) + (12 << 20));
  unsigned int* cnt = (unsigned int*)(ws + (80 << 10) + (16 << 20));

  hipMemsetAsync(cnt, 0, 4096, stream);
  make_table<<<80, 256, 0, stream>>>(embed, W_hx, b_hx, Txh);
  conv_w<<<4096, 256, 0, stream>>>(W_hh, Wb);
  init_h0<<<8192, 256, 0, stream>>>(Txh, x, Ha);

  // all 127 recurrence steps in one persistent cooperative kernel
  const u16* Wb_c = Wb;  const float* Txh_c = Txh;
  void* args[] = { (void*)&Wb_c, (void*)&Txh_c, (void*)&x, (void*)&b_hh,
                   (void*)&Ha, (void*)&Hb, (void*)&cnt };
  hipError_t ce = hipLaunchCooperativeKernel((const void*)rnn_persist,
                                             dim3(256), dim3(256),
                                             args, SMEM2_BYTES, stream);
  if (ce != hipSuccess) {
    // fallback: proven per-step dispatch path (round-3 behavior)
    for (int t = 1; t < S_; ++t) {
      const u16* hin = (t & 1) ? Ha : Hb;
      u16* hout = (t & 1) ? Hb : Ha;
      rnn_step<<<256, 256, SMEM_BYTES, stream>>>(hin, Wb, Txh, x, b_hh, hout, t);
    }
  }
  // t=127 (odd) wrote Hb
  out_softmax<<<B_, 256, 0, stream>>>(Hb, W_oh, b_oh, out);
}

// Round 7
// 4981.332 us; speedup vs baseline: 1.7583x; 1.7583x over previous
//
#include <hip/hip_runtime.h>
#include <stdint.h>
#include <stddef.h>

// Problem dims
#define B_ 1024
#define S_ 128
#define D_ 256
#define H_ 2048
#define O_ 10
#define V_ 10

// Step-GEMM: C[1024 x 2048] = Hin[1024 x 2048(K)] * W[2048(N) x 2048(K)]^T
//
// Round-7 (back to per-step dispatch; persistent abandoned — r8/r9 both show
// dispatch was never the bottleneck). Evidence: r1 saturated the LDS port at
// 84% of the 85 B/cyc b128 ceiling (192 KB/CU/iter over 2700 cyc); r3 cut
// bytes 25% but halved waves -> port underfed, same time. Fix: A NEVER
// touches LDS. W keeps r3's proven 3-stage global_load_lds staging (16 KB/
// stage); A-fragments load DIRECTLY from global via inline-asm
// global_load_dwordx4 (16 rows x 64 B contiguous = coalesced; same bytes the
// LDS path delivered). Inline asm + hand-counted vmcnt = compiler-proof
// pipeline (r6's C++ loads got collapsed to 92 VGPR / zero depth).
// Per-iter FIFO queue = [W(kt+1), A0..A3, W(kt+2)] -> waits 16/12/8/4
// (tail iters 12/8/4/0), sched_barrier(0) after each wait (rule 18).
// LDS traffic 2.0 -> 0.77 MB/CU/step; ONE barrier per K-iter (lgkm0-guarded).
// A+W slices stay XCD-L2-resident (2 MB + 2 MB) under the r3 XCD map.
#define BM 128
#define BN 64
#define BK 128
#define NKT (H_ / BK)                 // 16 K-iterations
#define NSTG 3
#define BSTG (BN * BK)                // 8192 u16 = 16 KB per W stage

typedef unsigned short u16;
typedef short v8s __attribute__((ext_vector_type(8)));    // 8 x bf16 (4 VGPRs)
typedef float v4f __attribute__((ext_vector_type(4)));    // 4 x f32 MFMA C/D
typedef u16 u16x4 __attribute__((ext_vector_type(4)));

__device__ __forceinline__ u16 f2bf(float f) {
  unsigned int u = __float_as_uint(f);
  u += 0x7FFFu + ((u >> 16) & 1u);   // RNE
  return (u16)(u >> 16);
}
__device__ __forceinline__ float bf2f(u16 h) {
  return __uint_as_float(((unsigned int)h) << 16);
}
__device__ __forceinline__ float fast_tanh(float x) {
  float e = __expf(2.0f * x);
  return 1.0f - 2.0f / (e + 1.0f);
}
__device__ __forceinline__ void gl2lds16(const void* g, void* l) {
  __builtin_amdgcn_global_load_lds(
      (const __attribute__((address_space(1))) uint32_t*)g,
      (__attribute__((address_space(3))) uint32_t*)l, 16, 0, 0);
}

// ---------------- Txh[v][h] = b_hx[h] + sum_d embed[v][d]*W_hx[h][d] ----------------
__global__ __launch_bounds__(256) void make_table(const float* __restrict__ embed,
                                                  const float* __restrict__ W_hx,
                                                  const float* __restrict__ b_hx,
                                                  float* __restrict__ Txh) {
  int idx = blockIdx.x * 256 + threadIdx.x;   // 10*2048 = 20480
  int v = idx >> 11, h = idx & 2047;
  const float4* e4 = (const float4*)(embed + v * D_);
  const float4* w4 = (const float4*)(W_hx + (size_t)h * D_);
  float s = b_hx[h];
#pragma unroll 4
  for (int d = 0; d < D_ / 4; ++d) {
    float4 a = e4[d], b = w4[d];
    s = fmaf(a.x, b.x, s); s = fmaf(a.y, b.y, s);
    s = fmaf(a.z, b.z, s); s = fmaf(a.w, b.w, s);
  }
  Txh[idx] = s;
}

// ---------------- W_hh (f32) -> bf16, same [N][K] layout ----------------
__global__ __launch_bounds__(256) void conv_w(const float* __restrict__ W,
                                              u16* __restrict__ Wb) {
  int i = blockIdx.x * 256 + threadIdx.x;
  float4 w = ((const float4*)W)[i];
  u16x4 o = { f2bf(w.x), f2bf(w.y), f2bf(w.z), f2bf(w.w) };
  ((u16x4*)Wb)[i] = o;
}

// ---------------- h0[b][j] = tanh(Txh[x[b,0]][j]) ----------------
__global__ __launch_bounds__(256) void init_h0(const float* __restrict__ Txh,
                                               const int* __restrict__ x,
                                               u16* __restrict__ H0) {
  int idx = blockIdx.x * 256 + threadIdx.x;   // 2M
  int b = idx >> 11, j = idx & 2047;
  int xv = x[b * S_];
  H0[idx] = f2bf(fast_tanh(Txh[xv * H_ + j]));
}

// ---------------- one recurrence step ----------------
// Hout[b][n] = tanh( sum_k Hin[b][k]*Wb[n][k] + Txh[x[b,t]][n] + b_hh[n] )
//
// W LDS tile: [64 rows][16 chunks of 8 bf16], chunk XOR-swizzled (slot(n,c)
// holds chunk c^(n&15); read (cc^lane16) with n&15==lane16 -> conflict-free,
// verified 0 SQ_LDS_BANK_CONFLICT rounds 0-3).
// A fragment (direct global): row = bm + wr*64 + i*16 + lane16,
// k = kt*128 + kc*32 + quad*8 -> byte addr = row*4096 + kt*256 + kc*64
// + quad*16. Base voffA per (i) covers row+quad; kt folded at runtime
// (4 adds/iter); kc is a literal 0/64/128/192 offset immediate.
//
// XCD swizzle (r3): each XCD owns 4 bm-groups (512 rows, 2 MB A) x 8
// bn-groups (512 cols, 2 MB W); W slice step-invariant -> L2-resident.

#define WAITV(N) asm volatile("s_waitcnt vmcnt(" #N ")" ::: "memory")
#define SB0 __builtin_amdgcn_sched_barrier(0)

__global__ __launch_bounds__(256, 1) void rnn_step(const u16* __restrict__ Hin,
                                                   const u16* __restrict__ Wb,
                                                   const float* __restrict__ Txh,
                                                   const int* __restrict__ x,
                                                   const float* __restrict__ b_hh,
                                                   u16* __restrict__ Hout,
                                                   int t) {
  __shared__ __align__(16) u16 Bst[NSTG][BSTG];   // 3 x 16 KB W stages

  const int tid = threadIdx.x;                 // 0..255 (4 waves, 1 per SIMD)
  const int bid = blockIdx.x;
  const int xcd = bid & 7;
  const int sl  = bid >> 3;
  const int xr = xcd >> 2, xc = xcd & 3;
  const int bm = (xr * 4 + (sl >> 3)) * BM;
  const int bn = (xc * 8 + (sl & 7)) * BN;

  const int w = tid >> 6, l = tid & 63;
  const int wr = w >> 1, wc = w & 1;           // wave tile rows wr*64, cols wc*32
  const int lane16 = l & 15, quad = l >> 4;
  const int wbase = w << 6;

  // W staging source offsets (r3-proven, swizzle on global side)
  unsigned offB[4];
#pragma unroll
  for (int i = 0; i < 4; ++i) {
    int s = i * 256 + tid;
    int n = s >> 4;
    int cg = (s & 15) ^ (n & 15);
    offB[i] = (unsigned)((bn + n) * H_ + cg * 8);
  }
  // A direct-load base byte-offsets (per m-subtile)
  unsigned voffA[4];
#pragma unroll
  for (int i = 0; i < 4; ++i)
    voffA[i] = (unsigned)(((bm + wr * 64 + i * 16 + lane16) * H_ + quad * 8) * 2);

#define STAGE_W(stg, kbase) do {                                            \
    u16* Bs_ = &Bst[stg][0];                                                \
    _Pragma("unroll")                                                       \
    for (int i_ = 0; i_ < 4; ++i_)                                          \
      gl2lds16(Wb + offB[i_] + (kbase), Bs_ + (size_t)(i_ * 256 + wbase) * 8); \
  } while (0)

  // 4 asm loads into one A register set; OFFLIT must be a literal (0/64/128/192)
#define ALD(SET, VK, OFFLIT) do {                                           \
    _Pragma("unroll")                                                       \
    for (int i_ = 0; i_ < 4; ++i_)                                          \
      asm volatile("global_load_dwordx4 %0, %1, %2 offset:%3"               \
                   : "=v"(SET[i_])                                          \
                   : "v"(VK[i_]), "s"(Hin), "n"(OFFLIT)                     \
                   : "memory");                                             \
  } while (0)

#define BSET(BV, KC) do {                                                   \
    const int cc_ = (KC) * 4 + quad;                                        \
    _Pragma("unroll")                                                       \
    for (int j_ = 0; j_ < 2; ++j_) {                                        \
      int n_ = wc * 32 + j_ * 16 + lane16;                                  \
      BV[j_] = *(const v8s*)&Bsb[(size_t)(n_ * 16 + (cc_ ^ lane16)) * 8];   \
    }                                                                       \
  } while (0)

#define MM(AV, BV) do {                                                     \
    _Pragma("unroll")                                                       \
    for (int i_ = 0; i_ < 4; ++i_)                                          \
      _Pragma("unroll")                                                     \
      for (int j_ = 0; j_ < 2; ++j_)                                        \
        acc[i_][j_] = __builtin_amdgcn_mfma_f32_16x16x32_bf16(              \
            AV[i_], BV[j_], acc[i_][j_], 0, 0, 0);                          \
  } while (0)

  v4f acc[4][2];
#pragma unroll
  for (int i = 0; i < 4; ++i)
#pragma unroll
    for (int j = 0; j < 2; ++j) acc[i][j] = (v4f){0.f, 0.f, 0.f, 0.f};

  // prologue: W stages 0,1 in flight; drain W0 (vmcnt(4)) and publish
  STAGE_W(0, 0);
  STAGE_W(1, BK);
  WAITV(4);
  __builtin_amdgcn_s_barrier();
  asm volatile("" ::: "memory");

  int cur = 0, pre = 2;
  for (int kt = 0; kt < NKT; ++kt) {
    // one barrier per iter: publishes W(kt) (drained in iter kt-1 / prologue)
    // and protects stage (kt+2)%3 from overwrite while still being read.
    asm volatile("s_waitcnt lgkmcnt(0)" ::: "memory");
    __builtin_amdgcn_s_barrier();
    asm volatile("" ::: "memory");

    // A loads FIRST (so A-waits never force-drain fresh W prefetch: FIFO)
    unsigned vk[4];
#pragma unroll
    for (int i = 0; i < 4; ++i) vk[i] = voffA[i] + (unsigned)(kt * 256);
    v8s a0[4], a1[4], a2[4], a3[4];
    ALD(a0, vk, 0);
    ALD(a1, vk, 64);
    ALD(a2, vk, 128);
    ALD(a3, vk, 192);
    if (kt + 2 < NKT) STAGE_W(pre, (kt + 2) * BK);

    const u16* Bsb = &Bst[cur][0];
    v8s bX[2], bY[2];
    BSET(bX, 0);
    BSET(bY, 1);
    // queue: [W(kt+1)4, A0 4, A1 4, A2 4, A3 4, W(kt+2)4] (steady)
    if (kt < NKT - 2) { WAITV(16); } else { WAITV(12); }
    SB0;
    MM(a0, bX);
    BSET(bX, 2);
    if (kt < NKT - 2) { WAITV(12); } else { WAITV(8); }
    SB0;
    MM(a1, bY);
    BSET(bY, 3);
    if (kt < NKT - 2) { WAITV(8); } else { WAITV(4); }
    SB0;
    MM(a2, bX);
    if (kt < NKT - 2) { WAITV(4); } else { WAITV(0); }
    SB0;
    MM(a3, bY);

    cur = (cur == 2) ? 0 : cur + 1;
    pre = (pre == 2) ? 0 : pre + 1;
  }
#undef STAGE_W
#undef ALD
#undef BSET
#undef MM

  // epilogue: C/D layout col=lane&15, row=quad*4+reg  [m89-verified]
  float bh[2];
#pragma unroll
  for (int j = 0; j < 2; ++j) bh[j] = b_hh[bn + wc * 32 + j * 16 + lane16];
#pragma unroll
  for (int i = 0; i < 4; ++i) {
#pragma unroll
    for (int r = 0; r < 4; ++r) {
      int row = bm + wr * 64 + i * 16 + quad * 4 + r;
      const float* trow = Txh + x[row * S_ + t] * H_;
      u16* orow = Hout + (size_t)row * H_;
#pragma unroll
      for (int j = 0; j < 2; ++j) {
        int col = bn + wc * 32 + j * 16 + lane16;
        float v = acc[i][j][r] + trow[col] + bh[j];
        orow[col] = f2bf(fast_tanh(v));
      }
    }
  }
}

// ---------------- o = hT @ W_oh^T + b_oh ; softmax over 10 ----------------
__global__ __launch_bounds__(256) void out_softmax(const u16* __restrict__ Hf,
                                                   const float* __restrict__ W_oh,
                                                   const float* __restrict__ b_oh,
                                                   float* __restrict__ out) {
  int b = blockIdx.x, tid = threadIdx.x;
  float hv[8];
  const u16* hr = Hf + (size_t)b * H_ + tid * 8;
#pragma unroll
  for (int u = 0; u < 8; ++u) hv[u] = bf2f(hr[u]);
  float acc[O_];
#pragma unroll
  for (int i = 0; i < O_; ++i) {
    const float* wr = W_oh + (size_t)i * H_ + tid * 8;
    float s = 0.f;
#pragma unroll
    for (int u = 0; u < 8; ++u) s = fmaf(hv[u], wr[u], s);
    acc[i] = s;
  }
#pragma unroll
  for (int off = 32; off > 0; off >>= 1)
#pragma unroll
    for (int i = 0; i < O_; ++i) acc[i] += __shfl_down(acc[i], off);
  __shared__ float red[4][O_];
  if ((tid & 63) == 0)
#pragma unroll
    for (int i = 0; i < O_; ++i) red[tid >> 6][i] = acc[i];
  __syncthreads();
  if (tid == 0) {
    float o[O_], mx = -1e30f;
#pragma unroll
    for (int i = 0; i < O_; ++i) {
      o[i] = red[0][i] + red[1][i] + red[2][i] + red[3][i] + b_oh[i];
      mx = fmaxf(mx, o[i]);
    }
    float se = 0.f;
#pragma unroll
    for (int i = 0; i < O_; ++i) { o[i] = __expf(o[i] - mx); se += o[i]; }
    float inv = 1.f / se;
#pragma unroll
    for (int i = 0; i < O_; ++i) out[b * O_ + i] = o[i] * inv;
  }
}

extern "C" void kernel_launch(void* const* d_in, const int* in_sizes, int n_in,
                              void* d_out, int out_size, void* d_ws, size_t ws_size,
                              hipStream_t stream) {
  const int*   x     = (const int*)  d_in[0];
  const float* embed = (const float*)d_in[1];
  const float* W_hx  = (const float*)d_in[2];
  const float* b_hx  = (const float*)d_in[3];
  const float* W_hh  = (const float*)d_in[4];
  const float* b_hh  = (const float*)d_in[5];
  const float* W_oh  = (const float*)d_in[6];
  const float* b_oh  = (const float*)d_in[7];
  float* out = (float*)d_out;

  // workspace: Txh 80KB | Wb 8MB | Ha 4MB | Hb 4MB  (~16.1 MB)
  char* ws = (char*)d_ws;
  float* Txh = (float*)ws;
  u16* Wb = (u16*)(ws + (80 << 10));
  u16* Ha = (u16*)(ws + (80 << 10) + (8 << 20));
  u16* Hb = (u16*)(ws + (80 << 10) + (12 << 20));

  make_table<<<80, 256, 0, stream>>>(embed, W_hx, b_hx, Txh);
  conv_w<<<4096, 256, 0, stream>>>(W_hh, Wb);
  init_h0<<<8192, 256, 0, stream>>>(Txh, x, Ha);

  for (int t = 1; t < S_; ++t) {
    const u16* hin = (t & 1) ? Ha : Hb;
    u16* hout = (t & 1) ? Hb : Ha;
    rnn_step<<<256, 256, 0, stream>>>(hin, Wb, Txh, x, b_hh, hout, t);
  }
  // t=127 (odd) wrote Hb
  out_softmax<<<B_, 256, 0, stream>>>(Hb, W_oh, b_oh, out);
}

// Round 8
// 2742.811 us; speedup vs baseline: 3.1933x; 1.8161x over previous
//
#include <hip/hip_runtime.h>
#include <stdint.h>
#include <stddef.h>

// Problem dims
#define B_ 1024
#define S_ 128
#define D_ 256
#define H_ 2048
#define O_ 10
#define V_ 10

// Step-GEMM: C[1024 x 2048] = Hin[1024 x 2048(K)] * W[2048(N) x 2048(K)]^T
//
// Round-8 = round-7 with the latency hole closed + rebalanced wave tile.
// r7 failed (38 us/step) because A-loads were consumed in the SAME K-iter
// they were issued (zero lead). Fix: A-loads go one full K-iter ahead into
// a double-buffered register set ar[2][8] (asm volatile -> compiler-proof,
// r6 lesson). Wave tile 32x64 (disjoint rows per wave): 8 A-loads/wave/iter,
// NO inter-wave A duplication -> L2 48 KB/iter (same as DMA path), LDS 80
// KB/iter (W only: 16 KB write + 64 KB read). Model: L2 ~820cy, LDS ~700-
// 940cy, MFMA 620cy, overlapped -> ~1300-1600 cy/iter vs r1's 2700.
// FIFO per iter: issue [A(kt+1)8, W(kt+2)4]; steady queue
// [A(kt)8, W(kt+1)4, A(kt+1)8, W(kt+2)4]; mid vmcnt(16) releases A(kt)
// (one iter of lead), end vmcnt(12) lands W(kt+1) before the single
// lgkm0-guarded barrier. Tail waits 12/8/0. sched_barrier(0) after every
// wait (rule 18). kt-loop fully unrolled -> kt&1 set index static (rule 20).
#define BM 128
#define BN 64
#define BK 128
#define NKT (H_ / BK)                 // 16 K-iterations
#define NSTG 3
#define BSTG (BN * BK)                // 8192 u16 = 16 KB per W stage

typedef unsigned short u16;
typedef short v8s __attribute__((ext_vector_type(8)));    // 8 x bf16 (4 VGPRs)
typedef float v4f __attribute__((ext_vector_type(4)));    // 4 x f32 MFMA C/D
typedef u16 u16x4 __attribute__((ext_vector_type(4)));

__device__ __forceinline__ u16 f2bf(float f) {
  unsigned int u = __float_as_uint(f);
  u += 0x7FFFu + ((u >> 16) & 1u);   // RNE
  return (u16)(u >> 16);
}
__device__ __forceinline__ float bf2f(u16 h) {
  return __uint_as_float(((unsigned int)h) << 16);
}
__device__ __forceinline__ float fast_tanh(float x) {
  float e = __expf(2.0f * x);
  return 1.0f - 2.0f / (e + 1.0f);
}
__device__ __forceinline__ void gl2lds16(const void* g, void* l) {
  __builtin_amdgcn_global_load_lds(
      (const __attribute__((address_space(1))) uint32_t*)g,
      (__attribute__((address_space(3))) uint32_t*)l, 16, 0, 0);
}

// ---------------- Txh[v][h] = b_hx[h] + sum_d embed[v][d]*W_hx[h][d] ----------------
__global__ __launch_bounds__(256) void make_table(const float* __restrict__ embed,
                                                  const float* __restrict__ W_hx,
                                                  const float* __restrict__ b_hx,
                                                  float* __restrict__ Txh) {
  int idx = blockIdx.x * 256 + threadIdx.x;   // 10*2048 = 20480
  int v = idx >> 11, h = idx & 2047;
  const float4* e4 = (const float4*)(embed + v * D_);
  const float4* w4 = (const float4*)(W_hx + (size_t)h * D_);
  float s = b_hx[h];
#pragma unroll 4
  for (int d = 0; d < D_ / 4; ++d) {
    float4 a = e4[d], b = w4[d];
    s = fmaf(a.x, b.x, s); s = fmaf(a.y, b.y, s);
    s = fmaf(a.z, b.z, s); s = fmaf(a.w, b.w, s);
  }
  Txh[idx] = s;
}

// ---------------- W_hh (f32) -> bf16, same [N][K] layout ----------------
__global__ __launch_bounds__(256) void conv_w(const float* __restrict__ W,
                                              u16* __restrict__ Wb) {
  int i = blockIdx.x * 256 + threadIdx.x;
  float4 w = ((const float4*)W)[i];
  u16x4 o = { f2bf(w.x), f2bf(w.y), f2bf(w.z), f2bf(w.w) };
  ((u16x4*)Wb)[i] = o;
}

// ---------------- h0[b][j] = tanh(Txh[x[b,0]][j]) ----------------
__global__ __launch_bounds__(256) void init_h0(const float* __restrict__ Txh,
                                               const int* __restrict__ x,
                                               u16* __restrict__ H0) {
  int idx = blockIdx.x * 256 + threadIdx.x;   // 2M
  int b = idx >> 11, j = idx & 2047;
  int xv = x[b * S_];
  H0[idx] = f2bf(fast_tanh(Txh[xv * H_ + j]));
}

// ---------------- one recurrence step ----------------
// Hout[b][n] = tanh( sum_k Hin[b][k]*Wb[n][k] + Txh[x[b,t]][n] + b_hh[n] )
//
// Wave w owns rows [bm + w*32, +32) x cols [bn, bn+64) (disjoint rows).
// W LDS tile [64 rows][16 chunks], XOR-swizzled slot(n,c)=c^(n&15); read
// (cc^lane16) with n&15==lane16 -> conflict-free (0 conflicts, rounds 0-7).
// A fragment direct from global: row = bm + w*32 + i*16 + lane16,
// byte = row*4096 + kt*256 + kc*64 + quad*16.
// XCD swizzle (r3): each XCD: 4 bm-groups (2 MB A) x 8 bn-groups (2 MB W),
// W slice step-invariant -> L2-resident.

#define WAITV(N) asm volatile("s_waitcnt vmcnt(" #N ")" ::: "memory")
#define SB0 __builtin_amdgcn_sched_barrier(0)

__global__ __launch_bounds__(256, 1) void rnn_step(const u16* __restrict__ Hin,
                                                   const u16* __restrict__ Wb,
                                                   const float* __restrict__ Txh,
                                                   const int* __restrict__ x,
                                                   const float* __restrict__ b_hh,
                                                   u16* __restrict__ Hout,
                                                   int t) {
  __shared__ __align__(16) u16 Bst[NSTG][BSTG];   // 3 x 16 KB W stages

  const int tid = threadIdx.x;                 // 0..255 (4 waves, 1 per SIMD)
  const int bid = blockIdx.x;
  const int xcd = bid & 7;
  const int sl  = bid >> 3;
  const int xr = xcd >> 2, xc = xcd & 3;
  const int bm = (xr * 4 + (sl >> 3)) * BM;
  const int bn = (xc * 8 + (sl & 7)) * BN;

  const int w = tid >> 6, l = tid & 63;
  const int lane16 = l & 15, quad = l >> 4;
  const int wbase = w << 6;

  // W staging source offsets (swizzle on global side; r3-proven)
  unsigned offB[4];
#pragma unroll
  for (int i = 0; i < 4; ++i) {
    int s = i * 256 + tid;
    int n = s >> 4;
    int cg = (s & 15) ^ (n & 15);
    offB[i] = (unsigned)((bn + n) * H_ + cg * 8);
  }
  // A direct-load base byte-offsets, one per m-subtile (i = 0,1)
  unsigned voffA[2];
#pragma unroll
  for (int i = 0; i < 2; ++i)
    voffA[i] = (unsigned)(((bm + w * 32 + i * 16 + lane16) * H_ + quad * 8) * 2);

#define STAGE_W(stg, kbase) do {                                            \
    u16* Bs_ = &Bst[stg][0];                                                \
    _Pragma("unroll")                                                       \
    for (int i_ = 0; i_ < 4; ++i_)                                          \
      gl2lds16(Wb + offB[i_] + (kbase), Bs_ + (size_t)(i_ * 256 + wbase) * 8); \
  } while (0)

#define ALD1(DST, VOFF, OFFLIT)                                             \
    asm volatile("global_load_dwordx4 %0, %1, %2 offset:%3"                 \
                 : "=v"(DST)                                                \
                 : "v"(VOFF), "s"(Hin), "n"(OFFLIT)                         \
                 : "memory")

  // issue the 8 A-loads of K-tile kt into set S (kc-major, i inner)
#define ALD8(S, KT) do {                                                    \
    unsigned vk0_ = voffA[0] + (unsigned)((KT) * 256);                      \
    unsigned vk1_ = voffA[1] + (unsigned)((KT) * 256);                      \
    ALD1(ar[S][0], vk0_, 0);   ALD1(ar[S][1], vk1_, 0);                     \
    ALD1(ar[S][2], vk0_, 64);  ALD1(ar[S][3], vk1_, 64);                    \
    ALD1(ar[S][4], vk0_, 128); ALD1(ar[S][5], vk1_, 128);                   \
    ALD1(ar[S][6], vk0_, 192); ALD1(ar[S][7], vk1_, 192);                   \
  } while (0)

#define BSET(BV, KC) do {                                                   \
    const int cc_ = (KC) * 4 + quad;                                        \
    _Pragma("unroll")                                                       \
    for (int j_ = 0; j_ < 4; ++j_) {                                        \
      int n_ = j_ * 16 + lane16;                                            \
      BV[j_] = *(const v8s*)&Bsb[(size_t)(n_ * 16 + (cc_ ^ lane16)) * 8];   \
    }                                                                       \
  } while (0)

#define MMK(S, KC, BV) do {                                                 \
    _Pragma("unroll")                                                       \
    for (int i_ = 0; i_ < 2; ++i_)                                          \
      _Pragma("unroll")                                                     \
      for (int j_ = 0; j_ < 4; ++j_)                                        \
        acc[i_][j_] = __builtin_amdgcn_mfma_f32_16x16x32_bf16(              \
            ar[S][(KC) * 2 + i_], BV[j_], acc[i_][j_], 0, 0, 0);            \
  } while (0)

  v4f acc[2][4];
#pragma unroll
  for (int i = 0; i < 2; ++i)
#pragma unroll
    for (int j = 0; j < 4; ++j) acc[i][j] = (v4f){0.f, 0.f, 0.f, 0.f};

  v8s ar[2][8];                                // A double-buffer (64 VGPR)

  // prologue: W(0), W(1) staged; A(0) into set 0; land W(0); publish.
  STAGE_W(0, 0);
  STAGE_W(1, BK);
  ALD8(0, 0);
  WAITV(12);            // FIFO [W0 4, W1 4, A0 8] -> drain W0
  __builtin_amdgcn_s_barrier();
  asm volatile("" ::: "memory");

#pragma unroll
  for (int kt = 0; kt < NKT; ++kt) {
    const int cs = kt & 1, ps = cs ^ 1;        // static under full unroll

    if (kt + 1 < NKT) ALD8(ps, kt + 1);        // A one iter ahead
    if (kt + 2 < NKT) STAGE_W((kt + 2) % 3, (kt + 2) * BK);

    // mid wait: A(kt) landed (issued one full iter ago).
    // steady FIFO: [A(kt)8, W(kt+1)4, A(kt+1)8, W(kt+2)4] -> newer = 16.
    if (kt == 0)            { WAITV(12); }     // [W1,A0 | A1,W2]: newer=12
    else if (kt < NKT - 2)  { WAITV(16); }
    else if (kt == NKT - 2) { WAITV(12); }     // no W(16): newer = W15+A15 = 12
    else                    { WAITV(0);  }     // last iter: drain
    SB0;

    const u16* Bsb = &Bst[kt % 3][0];
    v8s bX[4], bY[4];
    BSET(bX, 0);
    BSET(bY, 1);
    MMK(cs, 0, bX);
    BSET(bX, 2);
    MMK(cs, 1, bY);
    BSET(bY, 3);
    MMK(cs, 2, bX);
    MMK(cs, 3, bY);

    if (kt < NKT - 1) {
      // end wait: W(kt+1) landed before publishing barrier.
      if (kt < NKT - 2) { WAITV(12); }         // newer = A(kt+1)8 + W(kt+2)4
      else              { WAITV(8);  }         // kt=14: newer = A(15)8
      // lgkm0: this wave's stage-(kt%3) reads done before anyone overwrites
      // it (next iter issues W(kt+3) -> stage (kt%3)).
      asm volatile("s_waitcnt lgkmcnt(0)" ::: "memory");
      __builtin_amdgcn_s_barrier();
      asm volatile("" ::: "memory");
    }
  }
#undef STAGE_W
#undef ALD1
#undef ALD8
#undef BSET
#undef MMK

  // epilogue: C/D layout col=lane&15, row=quad*4+reg  [m89-verified]
  float bh[4];
#pragma unroll
  for (int j = 0; j < 4; ++j) bh[j] = b_hh[bn + j * 16 + lane16];
#pragma unroll
  for (int i = 0; i < 2; ++i) {
#pragma unroll
    for (int r = 0; r < 4; ++r) {
      int row = bm + w * 32 + i * 16 + quad * 4 + r;
      const float* trow = Txh + x[row * S_ + t] * H_;
      u16* orow = Hout + (size_t)row * H_;
#pragma unroll
      for (int j = 0; j < 4; ++j) {
        int col = bn + j * 16 + lane16;
        float v = acc[i][j][r] + trow[col] + bh[j];
        orow[col] = f2bf(fast_tanh(v));
      }
    }
  }
}

// ---------------- o = hT @ W_oh^T + b_oh ; softmax over 10 ----------------
__global__ __launch_bounds__(256) void out_softmax(const u16* __restrict__ Hf,
                                                   const float* __restrict__ W_oh,
                                                   const float* __restrict__ b_oh,
                                                   float* __restrict__ out) {
  int b = blockIdx.x, tid = threadIdx.x;
  float hv[8];
  const u16* hr = Hf + (size_t)b * H_ + tid * 8;
#pragma unroll
  for (int u = 0; u < 8; ++u) hv[u] = bf2f(hr[u]);
  float acc[O_];
#pragma unroll
  for (int i = 0; i < O_; ++i) {
    const float* wr = W_oh + (size_t)i * H_ + tid * 8;
    float s = 0.f;
#pragma unroll
    for (int u = 0; u < 8; ++u) s = fmaf(hv[u], wr[u], s);
    acc[i] = s;
  }
#pragma unroll
  for (int off = 32; off > 0; off >>= 1)
#pragma unroll
    for (int i = 0; i < O_; ++i) acc[i] += __shfl_down(acc[i], off);
  __shared__ float red[4][O_];
  if ((tid & 63) == 0)
#pragma unroll
    for (int i = 0; i < O_; ++i) red[tid >> 6][i] = acc[i];
  __syncthreads();
  if (tid == 0) {
    float o[O_], mx = -1e30f;
#pragma unroll
    for (int i = 0; i < O_; ++i) {
      o[i] = red[0][i] + red[1][i] + red[2][i] + red[3][i] + b_oh[i];
      mx = fmaxf(mx, o[i]);
    }
    float se = 0.f;
#pragma unroll
    for (int i = 0; i < O_; ++i) { o[i] = __expf(o[i] - mx); se += o[i]; }
    float inv = 1.f / se;
#pragma unroll
    for (int i = 0; i < O_; ++i) out[b * O_ + i] = o[i] * inv;
  }
}

extern "C" void kernel_launch(void* const* d_in, const int* in_sizes, int n_in,
                              void* d_out, int out_size, void* d_ws, size_t ws_size,
                              hipStream_t stream) {
  const int*   x     = (const int*)  d_in[0];
  const float* embed = (const float*)d_in[1];
  const float* W_hx  = (const float*)d_in[2];
  const float* b_hx  = (const float*)d_in[3];
  const float* W_hh  = (const float*)d_in[4];
  const float* b_hh  = (const float*)d_in[5];
  const float* W_oh  = (const float*)d_in[6];
  const float* b_oh  = (const float*)d_in[7];
  float* out = (float*)d_out;

  // workspace: Txh 80KB | Wb 8MB | Ha 4MB | Hb 4MB  (~16.1 MB)
  char* ws = (char*)d_ws;
  float* Txh = (float*)ws;
  u16* Wb = (u16*)(ws + (80 << 10));
  u16* Ha = (u16*)(ws + (80 << 10) + (8 << 20));
  u16* Hb = (u16*)(ws + (80 << 10) + (12 << 20));

  make_table<<<80, 256, 0, stream>>>(embed, W_hx, b_hx, Txh);
  conv_w<<<4096, 256, 0, stream>>>(W_hh, Wb);
  init_h0<<<8192, 256, 0, stream>>>(Txh, x, Ha);

  for (int t = 1; t < S_; ++t) {
    const u16* hin = (t & 1) ? Ha : Hb;
    u16* hout = (t & 1) ? Hb : Ha;
    rnn_step<<<256, 256, 0, stream>>>(hin, Wb, Txh, x, b_hh, hout, t);
  }
  // t=127 (odd) wrote Hb
  out_softmax<<<B_, 256, 0, stream>>>(Hb, W_oh, b_oh, out);
}